// Round 13
// baseline (221.641 us; speedup 1.0000x reference)
//
#include <hip/hip_runtime.h>
#include <math.h>

#define T_DIM 2048
#define S_DIM 2048
#define D_DIM 64
#define BH_DIM 32
#define U_SEL 614
#define QROWS 32
#define LOG_S_D 7.624618986159398
#define LOG2E_F 1.4426950408889634f
#define LN2_D 0.6931471805599453
#define SCL_Q (0.125f * LOG2E_F)  // q scale folded with log2e: scores in log2 domain

typedef __attribute__((ext_vector_type(8))) short bf16x8;
typedef __attribute__((ext_vector_type(4))) short bf16x4;
typedef __attribute__((ext_vector_type(4))) float f32x4;

__device__ __forceinline__ unsigned short bf16_rne(float x) {
  unsigned u = __float_as_uint(x);
  u += 0x7FFF + ((u >> 16) & 1);
  return (unsigned short)(u >> 16);
}
__device__ __forceinline__ float bf16_to_f(unsigned short h) {
  return __uint_as_float(((unsigned)h) << 16);
}
// ROUND-8 LESSON: raw inline-asm v_exp_f32 is WRONG (TRANS hazard needs
// compiler-inserted waits; absmax 0.25). The BUILTIN is safe (compiler-managed)
// and skips OCML's ~5-instr denormal guards; inputs bounded by the ±50 clip.
#if defined(__has_builtin)
#if __has_builtin(__builtin_amdgcn_exp2f)
#define EXP2_HW(x) __builtin_amdgcn_exp2f(x)
#endif
#endif
#ifndef EXP2_HW
#define EXP2_HW(x) exp2f(x)
#endif

#define GLD_LDS16(g, l)                                                        \
  __builtin_amdgcn_global_load_lds(                                            \
      (const __attribute__((address_space(1))) unsigned int*)(const void*)(g), \
      (__attribute__((address_space(3))) unsigned int*)(void*)(l), 16, 0, 0)

// stage 16 KB image: 4 waves x 4 instr x 64 lanes x 16 B
__device__ __forceinline__ void stage_img16(const unsigned short* __restrict__ g,
                                            unsigned short* l, int lane, int w) {
#pragma unroll
  for (int it = 0; it < 4; ++it) {
    const int chunk = it * 4 + w;
    GLD_LDS16((const char*)g + chunk * 1024 + lane * 16, (char*)l + chunk * 1024);
  }
}

// swizzled image, 64-wide rows: element (r,d) at r*64 + ((d>>3)^(r&7))*8 + (d&7)
__device__ __forceinline__ bf16x8 ldfrag_sw(const unsigned short* buf, int row, int chunk) {
  return *(const bf16x8*)(buf + (row << 6) + (((chunk) ^ (row & 7)) << 3));
}
// two stacked 64-row images (rows 0..127)
__device__ __forceinline__ bf16x8 ldfrag_k128(const unsigned short* buf, int row, int chunk) {
  return *(const bf16x8*)(buf + ((row >> 6) << 12) + ((row & 63) << 6) +
                          (((chunk) ^ (row & 7)) << 3));
}

// ====== convert: K,Q -> 64-row tiles [hi 8KB | lo 8KB] swizzled (kl_score);
// K additionally -> QK-consumption-ordered hi image kcimg (Phase C direct-reg);
// V -> PV-ordered fragment images; zero(out).
// kcimg per 128-s tile: [w:4][mt:2][kc:2] 1KB blocks, block = [quad:4][l15:16][8d],
// element (w,mt,kc,quad,l15,j) = K[s=w*32+mt*16+l15][d=kc*32+quad*8+j].
// V layout per 128-s tile: [w:4][dt:4][quad:4][l15:16][8s],
// element = v[s=w*32+quad*8+j][d=dt*16+l15].
__global__ __launch_bounds__(256) void convert_kernel(
    const float* __restrict__ kin, const float* __restrict__ vin,
    const float* __restrict__ qin, unsigned short* __restrict__ kimg,
    unsigned short* __restrict__ vt_g, unsigned short* __restrict__ qimg,
    unsigned short* __restrict__ kcimg, float* __restrict__ out) {
  __shared__ float vld[128][65];
  const int jb = blockIdx.x;
  const int tid = threadIdx.x;
  if (jb < 2048) {  // K (jb<1024) or Q (1024..2047): 32 bh x 32 tiles of 64 rows
    const bool isq = jb >= 1024;
    const int jj = jb & 1023;
    const int bh = jj >> 5, tl = jj & 31;
    const float* src = (isq ? qin : kin) + ((size_t)bh * 2048 + tl * 64) * 64;
    unsigned short* dst = (isq ? qimg : kimg) + (size_t)(bh * 32 + tl) * 8192;
    unsigned short* kcd = kcimg + (size_t)(bh * 16 + (tl >> 1)) * 8192;
    const float scl = isq ? SCL_Q : 1.0f;
#pragma unroll
    for (int g = 0; g < 2; ++g) {
      const int flat = g * 256 + tid;  // 512 chunks = 64 rows x 8
      const int r = flat >> 3, c = flat & 7;
      const float4 f0 = *(const float4*)(src + r * 64 + c * 8);
      const float4 f1 = *(const float4*)(src + r * 64 + c * 8 + 4);
      const float xs[8] = {f0.x, f0.y, f0.z, f0.w, f1.x, f1.y, f1.z, f1.w};
      bf16x8 hv, lv;
#pragma unroll
      for (int j = 0; j < 8; ++j) {
        const float x = xs[j] * scl;
        const unsigned short h = bf16_rne(x);
        hv[j] = (short)h;
        lv[j] = (short)bf16_rne(x - bf16_to_f(h));
      }
      const int base = (r << 6) + ((c ^ (r & 7)) << 3);
      *(bf16x8*)(dst + base) = hv;
      *(bf16x8*)(dst + 4096 + base) = lv;
      if (!isq) {  // PV/QK-ordered hi copy for Phase C
        const int s_local = ((tl & 1) << 6) + r;
        const int wv = s_local >> 5, mtk = (r >> 4) & 1, kcc = c >> 2, qdd = c & 3;
        *(bf16x8*)(kcd + (wv * 4 + mtk * 2 + kcc) * 512 + qdd * 128 + ((r & 15) << 3)) = hv;
      }
    }
  } else if (jb < 2560) {  // V fragment images (PV consumption order)
    const int jv = jb - 2048;
    const int bh = jv >> 4, tl = jv & 15;
    const float* src = vin + ((size_t)bh * 2048 + tl * 128) * 64;
#pragma unroll
    for (int g = 0; g < 8; ++g) {
      const int f = g * 256 + tid;
      const int r = f >> 4, c4 = f & 15;
      const float4 x = *(const float4*)(src + r * 64 + c4 * 4);
      vld[r][c4 * 4 + 0] = x.x;
      vld[r][c4 * 4 + 1] = x.y;
      vld[r][c4 * 4 + 2] = x.z;
      vld[r][c4 * 4 + 3] = x.w;
    }
    __syncthreads();
    unsigned short* dst = vt_g + (size_t)(bh * 16 + tl) * 8192;
#pragma unroll
    for (int g = 0; g < 4; ++g) {
      const int oc = g * 256 + tid;  // 1024 fragments of 8 bf16
      const int w4 = oc >> 8, dt = (oc >> 6) & 3, qd = (oc >> 4) & 3, l = oc & 15;
      bf16x8 hv;
#pragma unroll
      for (int j = 0; j < 8; ++j)
        hv[j] = (short)bf16_rne(vld[w4 * 32 + qd * 8 + j][dt * 16 + l]);
      *(bf16x8*)(dst + oc * 8) = hv;
    }
  } else {  // zero d_out: 512 blocks x 2048 float4
    float4* o4 = (float4*)out;
    const size_t b = (size_t)(jb - 2560);
#pragma unroll
    for (int g = 0; g < 8; ++g)
      o4[b * 2048 + g * 256 + tid] = make_float4(0.f, 0.f, 0.f, 0.f);
  }
}

// ====== Phase A: partial (Z,W) per (t-row, s-half), bf16x3 MFMA, BK=64 dbuf ======
// grid 1024: bh = b&31 (XCD-local), ttile = (b>>5)&15, shalf = b>>9.
// ROUND-6 LESSON: co-resident same-bh blocks MUST walk the same K stream in
// lockstep (shalf 2-way only). K stays LDS-staged here: all 4 waves read the
// SAME K tile (4-way reuse) — unlike Phase C.
__global__ __launch_bounds__(256, 2) void kl_score_mfma(
    const unsigned short* __restrict__ qimg, const unsigned short* __restrict__ kimg,
    float2* __restrict__ zw) {
  __shared__ __align__(16) unsigned short lbuf[2][8192];  // 2 x 16 KB
  const int b = blockIdx.x;
  const int bh = b & 31;
  const int tt = (b >> 5) & 15;
  const int shalf = b >> 9;
  const int tid = threadIdx.x;
  const int lane = tid & 63, w = tid >> 6, quad = lane >> 4, l15 = lane & 15;
  const unsigned short* qb = qimg + (size_t)(bh * 32 + tt * 2) * 8192;
  const unsigned short* kb = kimg + (size_t)bh * (32 * 8192);
  const int tg0 = shalf * 16;

  // stage the 2 q tiles (rows 0-63 -> lbuf[0], rows 64-127 -> lbuf[1])
  stage_img16(qb, &lbuf[0][0], lane, w);
  stage_img16(qb + 8192, &lbuf[1][0], lane, w);
  __syncthreads();

  bf16x8 ah[2][2], al[2][2];  // persistent q A-fragments (wave w: t-rows w*32..w*32+31)
#pragma unroll
  for (int rt = 0; rt < 2; ++rt) {
    const int row = w * 32 + rt * 16 + l15;
    const unsigned short* lb = &lbuf[row >> 6][0];  // [hi 4096 | lo 4096] per tile
    const int r64 = row & 63;
#pragma unroll
    for (int kc = 0; kc < 2; ++kc) {
      const int off = (r64 << 6) + (((kc * 4 + quad) ^ (r64 & 7)) << 3);
      ah[rt][kc] = *(const bf16x8*)(lb + off);
      al[rt][kc] = *(const bf16x8*)(lb + 4096 + off);
    }
  }
  __syncthreads();  // all q frags in registers; lbuf free

  stage_img16(kb + (size_t)tg0 * 8192, &lbuf[0][0], lane, w);
  __syncthreads();  // drain tile 0

  float Zf[8], Wf[8];
#pragma unroll
  for (int i = 0; i < 8; ++i) { Zf[i] = 0.f; Wf[i] = 0.f; }

  for (int t = 0; t < 16; ++t) {
    if (t < 15)
      stage_img16(kb + (size_t)(tg0 + t + 1) * 8192, &lbuf[(t + 1) & 1][0], lane, w);
    const unsigned short* cb = &lbuf[t & 1][0];  // [hi 4096 | lo 4096] elems, 64 rows

    f32x4 acc[2][4];
#pragma unroll
    for (int rt = 0; rt < 2; ++rt)
#pragma unroll
      for (int ct = 0; ct < 4; ++ct) acc[rt][ct] = (f32x4){0.f, 0.f, 0.f, 0.f};

#pragma unroll
    for (int ct = 0; ct < 4; ++ct) {
      const int srow = ct * 16 + l15;
      const bf16x8 bh0 = ldfrag_sw(cb, srow, quad);
      const bf16x8 bl0 = ldfrag_sw(cb + 4096, srow, quad);
      const bf16x8 bh1 = ldfrag_sw(cb, srow, 4 + quad);
      const bf16x8 bl1 = ldfrag_sw(cb + 4096, srow, 4 + quad);
#pragma unroll
      for (int rt = 0; rt < 2; ++rt) {
        f32x4 c = acc[rt][ct];
        c = __builtin_amdgcn_mfma_f32_16x16x32_bf16(ah[rt][0], bh0, c, 0, 0, 0);
        c = __builtin_amdgcn_mfma_f32_16x16x32_bf16(al[rt][0], bh0, c, 0, 0, 0);
        c = __builtin_amdgcn_mfma_f32_16x16x32_bf16(ah[rt][0], bl0, c, 0, 0, 0);
        c = __builtin_amdgcn_mfma_f32_16x16x32_bf16(ah[rt][1], bh1, c, 0, 0, 0);
        c = __builtin_amdgcn_mfma_f32_16x16x32_bf16(al[rt][1], bh1, c, 0, 0, 0);
        c = __builtin_amdgcn_mfma_f32_16x16x32_bf16(ah[rt][1], bl1, c, 0, 0, 0);
        acc[rt][ct] = c;
      }
    }

    // no-max epilogue (log2 domain): e = 2^t, W += e*t  (fp32 accumulators)
#pragma unroll
    for (int rt = 0; rt < 2; ++rt)
#pragma unroll
      for (int r = 0; r < 4; ++r) {
        float zp = 0.f, wp = 0.f;
#pragma unroll
        for (int ct = 0; ct < 4; ++ct) {
          const float tv = acc[rt][ct][r];
          const float e = EXP2_HW(tv);
          zp += e;
          wp = fmaf(e, tv, wp);
        }
        Zf[rt * 4 + r] += zp;
        Wf[rt * 4 + r] += wp;
      }
    __syncthreads();  // readers done; drains prefetch of t+1
  }

#pragma unroll
  for (int i = 0; i < 8; ++i) {
    float Zt = Zf[i], Wt = Wf[i];
#pragma unroll
    for (int mask = 1; mask <= 8; mask <<= 1) {
      Zt += __shfl_xor(Zt, mask);
      Wt += __shfl_xor(Wt, mask);
    }
    if (l15 == 0) {
      const int row = tt * 128 + w * 32 + (i >> 2) * 16 + quad * 4 + (i & 3);
      zw[((size_t)shalf * 32 + bh) * 2048 + row] = make_float2(Zt, Wt);
    }
  }
}

// ====== Phase B: kl from (Z,W) halves + exact top-614, bitonic, 1024 threads ======
__global__ __launch_bounds__(1024) void topk_kernel(const float2* __restrict__ zw,
                                                    int* __restrict__ topk) {
  __shared__ float sv[2048];
  __shared__ int si[2048];
  const int bh = blockIdx.x;
  const int tid = threadIdx.x;
  for (int i = tid; i < 2048; i += 1024) {
    const float2 a = zw[(size_t)bh * 2048 + i];
    const float2 c = zw[(size_t)(32 + bh) * 2048 + i];
    const double Z = (double)a.x + (double)c.x;
    const double W = (double)a.y + (double)c.y;
    sv[i] = (float)(LN2_D * (W / Z) - log(Z) + LOG_S_D);
    si[i] = i;
  }
  __syncthreads();
  for (int kk = 2; kk <= 2048; kk <<= 1) {
    for (int j = kk >> 1; j > 0; j >>= 1) {
      const int p = tid;
      const int i = ((p & ~(j - 1)) << 1) | (p & (j - 1));
      const int pr = i | j;
      const float v1 = sv[i], v2 = sv[pr];
      const int i1 = si[i], i2 = si[pr];
      const bool beforePI = (v2 > v1) || (v2 == v1 && i2 < i1);
      const bool dirDesc = ((i & kk) == 0);
      const bool doSwap = dirDesc ? beforePI : !beforePI;
      if (doSwap) { sv[i] = v2; sv[pr] = v1; si[i] = i2; si[pr] = i1; }
      __syncthreads();
    }
  }
  for (int i = tid; i < U_SEL; i += 1024) topk[bh * U_SEL + i] = si[i];
}

// ====== Phase C: bf16 MFMA attention, BARRIER-FREE main loop ======
// ROUND-11/12 AUDIT EXTENDED: K (like V) has ZERO intra-block reuse — wave w
// owns s-rows [w*32,w*32+32) exclusively. Both K and V now load direct to
// registers from consumption-ordered global images (coalesced 1 KB bursts).
// The hot loop has NO __syncthreads (ps is wave-local; LDS only for q staging
// and output merge). LDS ~19 KB; grid 768 = 3 balanced blocks/CU; 12 waves/CU
// of free-running TLP hide all latency. Per-XCD same-bh K+V stream = 2 MB,
// fully L2-resident.
struct __align__(16) SmC {
  union { unsigned short qs[QROWS * 64]; unsigned short ps[4][QROWS * 40]; } c;  // 10 KB
  float obuf[QROWS * 64];  // 8 KB
  float zred[4][QROWS];    // 0.5 KB
};

// grid 768: bh = b&31 (XCD-affine), lt = b>>5 in [0,24)
__global__ __launch_bounds__(256, 3) void sparse_attn_mfma(
    const float* __restrict__ q, const unsigned short* __restrict__ kcimg,
    const unsigned short* __restrict__ vt_g, const int* __restrict__ topk,
    float* __restrict__ out) {
  __shared__ SmC sm;
  const int b = blockIdx.x;
  const int bh = b & 31;
  const int l0 = (b >> 5) * QROWS;
  const int tid = threadIdx.x;
  const int lane = tid & 63, w = tid >> 6, quad = lane >> 4, l15 = lane & 15;
  const float* qb = q + (size_t)bh * (2048 * 64);
  const char* kcb = (const char*)(kcimg + (size_t)bh * (16 * 8192));
  const char* vtb = (const char*)(vt_g + (size_t)bh * (16 * 8192));
  const int* tkb = topk + bh * U_SEL;

  {  // gather 32 selected q rows -> bf16 * (0.125*log2e), swizzled image in LDS
    const int r = tid >> 3, c = tid & 7;  // 256 chunks = 32 rows x 8
    const int l = l0 + r;
    const int row = (l < U_SEL) ? tkb[l] : tkb[0];
    const float4 f0 = *(const float4*)(qb + (size_t)row * 64 + c * 8);
    const float4 f1 = *(const float4*)(qb + (size_t)row * 64 + c * 8 + 4);
    const float xs[8] = {f0.x, f0.y, f0.z, f0.w, f1.x, f1.y, f1.z, f1.w};
    bf16x8 hv;
#pragma unroll
    for (int j = 0; j < 8; ++j) hv[j] = (short)bf16_rne(xs[j] * SCL_Q);
    *(bf16x8*)&sm.c.qs[(r << 6) + ((c ^ (r & 7)) << 3)] = hv;
  }
  __syncthreads();  // qs ready

  bf16x8 qf[2][2];  // persistent q B-fragments (32 rows -> 2 nt tiles)
#pragma unroll
  for (int nt = 0; nt < 2; ++nt)
#pragma unroll
    for (int kc = 0; kc < 2; ++kc)
      qf[nt][kc] = ldfrag_sw(sm.c.qs, nt * 16 + l15, kc * 4 + quad);
  __syncthreads();  // all waves done reading qs; ps (same bytes) may be written

  float zrun[2] = {0.f, 0.f};
  f32x4 oacc[2][4];
#pragma unroll
  for (int a = 0; a < 2; ++a)
#pragma unroll
    for (int b2 = 0; b2 < 4; ++b2) oacc[a][b2] = (f32x4){0.f, 0.f, 0.f, 0.f};

  for (int st = 0; st < 16; ++st) {
    // K fragments: coalesced direct-to-register (1 KB/wave per (mt,kc))
    const char* kp = kcb + (size_t)st * 16384;
    bf16x8 af[2][2];
#pragma unroll
    for (int mt = 0; mt < 2; ++mt)
#pragma unroll
      for (int kc = 0; kc < 2; ++kc)
        af[mt][kc] = *(const bf16x8*)(kp + ((w * 4 + mt * 2 + kc) << 10) + lane * 16);
    // V fragments: coalesced direct-to-register (1 KB/wave per dt)
    const char* vp = vtb + (size_t)st * 16384;
    bf16x8 vbf[4];
#pragma unroll
    for (int dt = 0; dt < 4; ++dt)
      vbf[dt] = *(const bf16x8*)(vp + ((w * 4 + dt) << 10) + lane * 16);

    // S^T = K·q^T : C[m=s][n=qr]; wave w owns s in [w*32, w*32+32)
    f32x4 sacc[2][2];
    __builtin_amdgcn_s_setprio(1);
#pragma unroll
    for (int mt = 0; mt < 2; ++mt)
#pragma unroll
      for (int nt = 0; nt < 2; ++nt) {
        f32x4 c = (f32x4){0.f, 0.f, 0.f, 0.f};
        c = __builtin_amdgcn_mfma_f32_16x16x32_bf16(af[mt][0], qf[nt][0], c, 0, 0, 0);
        c = __builtin_amdgcn_mfma_f32_16x16x32_bf16(af[mt][1], qf[nt][1], c, 0, 0, 0);
        sacc[mt][nt] = c;
      }
    __builtin_amdgcn_s_setprio(0);

    // no-max: p = 2^t; wave-local ps round-trip (no barrier needed)
#pragma unroll
    for (int nt = 0; nt < 2; ++nt) {
      float zl = 0.f;
#pragma unroll
      for (int mt = 0; mt < 2; ++mt) {
        bf16x4 pw;
#pragma unroll
        for (int r = 0; r < 4; ++r) {
          const float p = EXP2_HW(sacc[mt][nt][r]);
          zl += p;
          pw[r] = (short)bf16_rne(p);
        }
        *(bf16x4*)&sm.c.ps[w][(nt * 16 + l15) * 40 + mt * 16 + quad * 4] = pw;
      }
      zrun[nt] += zl;
    }

    // PV: O[qr][d] += P[qr][s]·V[s][d]  (K and V already in registers)
    __builtin_amdgcn_s_setprio(1);
#pragma unroll
    for (int mtq = 0; mtq < 2; ++mtq) {
      const bf16x8 pa = *(const bf16x8*)&sm.c.ps[w][(mtq * 16 + l15) * 40 + quad * 8];
#pragma unroll
      for (int dt = 0; dt < 4; ++dt)
        oacc[mtq][dt] = __builtin_amdgcn_mfma_f32_16x16x32_bf16(pa, vbf[dt], oacc[mtq][dt], 0, 0, 0);
    }
    __builtin_amdgcn_s_setprio(0);
    // no barrier: next iteration's K/V go to registers, ps is wave-local
  }

  // Z: reduce over quads in-wave, stash per-wave rows
#pragma unroll
  for (int nt = 0; nt < 2; ++nt) {
    float z = zrun[nt];
    z += __shfl_xor(z, 16);
    z += __shfl_xor(z, 32);
    if (quad == 0) sm.zred[w][nt * 16 + l15] = z;
  }
  for (int i = tid; i < QROWS * 64; i += 256) sm.obuf[i] = 0.f;
  __syncthreads();
#pragma unroll
  for (int mtq = 0; mtq < 2; ++mtq)
#pragma unroll
    for (int r = 0; r < 4; ++r) {
      const int qr = mtq * 16 + quad * 4 + r;
#pragma unroll
      for (int dt = 0; dt < 4; ++dt)
        atomicAdd(&sm.obuf[qr * 64 + dt * 16 + l15], oacc[mtq][dt][r]);
    }
  __syncthreads();
  {  // normalized direct store: 32 rows x 4 segs = 128 work items
    if (tid < QROWS * 4) {
      const int qr = tid >> 2, seg = tid & 3;
      const int l = l0 + qr;
      if (l < U_SEL) {
        const float Zt = sm.zred[0][qr] + sm.zred[1][qr] +
                         sm.zred[2][qr] + sm.zred[3][qr];
        const float inv = 1.0f / Zt;
        const int row = tkb[l];
        float* op = &out[((size_t)bh * T_DIM + row) * 64 + seg * 16];
        const float* ob = &sm.obuf[qr * 64 + seg * 16];
#pragma unroll
        for (int j = 0; j < 4; ++j) {
          float4 o;
          o.x = ob[j * 4 + 0] * inv;
          o.y = ob[j * 4 + 1] * inv;
          o.z = ob[j * 4 + 2] * inv;
          o.w = ob[j * 4 + 3] * inv;
          *(float4*)&op[j * 4] = o;
        }
      }
    }
  }
}

extern "C" void kernel_launch(void* const* d_in, const int* in_sizes, int n_in,
                              void* d_out, int out_size, void* d_ws, size_t ws_size,
                              hipStream_t stream) {
  const float* q = (const float*)d_in[0];
  const float* k = (const float*)d_in[1];
  const float* v = (const float*)d_in[2];
  float* out = (float*)d_out;
  // workspace: zw 1MB | topk 80KB | kimg 16MB | vt 8MB | qimg 16MB | kcimg 8MB (~49.3MB)
  char* ws = (char*)d_ws;
  float2* zw = (float2*)ws;                                  // [2][32][2048] float2
  int* topk = (int*)(ws + 1048576);
  unsigned short* kimg = (unsigned short*)(ws + 1310720);    // 32 bh x 32 tiles x 16 KB
  unsigned short* vt_g = (unsigned short*)(ws + 18087936);   // 32 bh x 16 tiles x 16 KB
  unsigned short* qimg = (unsigned short*)(ws + 26476544);   // 32 bh x 32 tiles x 16 KB
  unsigned short* kcimg = (unsigned short*)(ws + 43253760);  // 32 bh x 16 tiles x 16 KB

  convert_kernel<<<dim3(3072), dim3(256), 0, stream>>>(k, v, q, kimg, vt_g, qimg, kcimg, out);
  kl_score_mfma<<<dim3(1024), dim3(256), 0, stream>>>(qimg, kimg, zw);
  topk_kernel<<<dim3(BH_DIM), dim3(1024), 0, stream>>>(zw, topk);
  sparse_attn_mfma<<<dim3(768), dim3(256), 0, stream>>>(q, kcimg, vt_g, topk, out);
}

// Round 14
// 218.845 us; speedup vs baseline: 1.0128x; 1.0128x over previous
//
#include <hip/hip_runtime.h>
#include <math.h>

#define T_DIM 2048
#define S_DIM 2048
#define D_DIM 64
#define BH_DIM 32
#define U_SEL 614
#define QROWS 32
#define LOG_S_D 7.624618986159398
#define LOG2E_F 1.4426950408889634f
#define LN2_D 0.6931471805599453
#define SCL_Q (0.125f * LOG2E_F)  // q scale folded with log2e: scores in log2 domain

typedef __attribute__((ext_vector_type(8))) short bf16x8;
typedef __attribute__((ext_vector_type(4))) short bf16x4;
typedef __attribute__((ext_vector_type(4))) float f32x4;

__device__ __forceinline__ unsigned short bf16_rne(float x) {
  unsigned u = __float_as_uint(x);
  u += 0x7FFF + ((u >> 16) & 1);
  return (unsigned short)(u >> 16);
}
__device__ __forceinline__ float bf16_to_f(unsigned short h) {
  return __uint_as_float(((unsigned)h) << 16);
}
// ROUND-8 LESSON: raw inline-asm v_exp_f32 is WRONG (TRANS hazard needs
// compiler-inserted waits; absmax 0.25). The BUILTIN is safe (compiler-managed)
// and skips OCML's ~5-instr denormal guards; inputs bounded by the ±50 clip.
#if defined(__has_builtin)
#if __has_builtin(__builtin_amdgcn_exp2f)
#define EXP2_HW(x) __builtin_amdgcn_exp2f(x)
#endif
#endif
#ifndef EXP2_HW
#define EXP2_HW(x) exp2f(x)
#endif

#define GLD_LDS16(g, l)                                                        \
  __builtin_amdgcn_global_load_lds(                                            \
      (const __attribute__((address_space(1))) unsigned int*)(const void*)(g), \
      (__attribute__((address_space(3))) unsigned int*)(void*)(l), 16, 0, 0)

// stage 16 KB image: 4 waves x 4 instr x 64 lanes x 16 B
__device__ __forceinline__ void stage_img16(const unsigned short* __restrict__ g,
                                            unsigned short* l, int lane, int w) {
#pragma unroll
  for (int it = 0; it < 4; ++it) {
    const int chunk = it * 4 + w;
    GLD_LDS16((const char*)g + chunk * 1024 + lane * 16, (char*)l + chunk * 1024);
  }
}

// swizzled image, 64-wide rows: element (r,d) at r*64 + ((d>>3)^(r&7))*8 + (d&7)
__device__ __forceinline__ bf16x8 ldfrag_sw(const unsigned short* buf, int row, int chunk) {
  return *(const bf16x8*)(buf + (row << 6) + (((chunk) ^ (row & 7)) << 3));
}

// ====== convert: K,Q -> 64-row tiles [hi 8KB | lo 8KB] swizzled (kl_score);
// K additionally -> QK-consumption-ordered hi image kcimg (Phase C direct-reg);
// V -> PV-ordered fragment images; zero(out).
// kcimg per 128-s tile: [w:4][mt:2][kc:2] 1KB blocks, block = [quad:4][l15:16][8d],
// element (w,mt,kc,quad,l15,j) = K[s=w*32+mt*16+l15][d=kc*32+quad*8+j].
// V layout per 128-s tile: [w:4][dt:4][quad:4][l15:16][8s],
// element = v[s=w*32+quad*8+j][d=dt*16+l15].
__global__ __launch_bounds__(256) void convert_kernel(
    const float* __restrict__ kin, const float* __restrict__ vin,
    const float* __restrict__ qin, unsigned short* __restrict__ kimg,
    unsigned short* __restrict__ vt_g, unsigned short* __restrict__ qimg,
    unsigned short* __restrict__ kcimg, float* __restrict__ out) {
  __shared__ float vld[128][65];
  const int jb = blockIdx.x;
  const int tid = threadIdx.x;
  if (jb < 2048) {  // K (jb<1024) or Q (1024..2047): 32 bh x 32 tiles of 64 rows
    const bool isq = jb >= 1024;
    const int jj = jb & 1023;
    const int bh = jj >> 5, tl = jj & 31;
    const float* src = (isq ? qin : kin) + ((size_t)bh * 2048 + tl * 64) * 64;
    unsigned short* dst = (isq ? qimg : kimg) + (size_t)(bh * 32 + tl) * 8192;
    unsigned short* kcd = kcimg + (size_t)(bh * 16 + (tl >> 1)) * 8192;
    const float scl = isq ? SCL_Q : 1.0f;
#pragma unroll
    for (int g = 0; g < 2; ++g) {
      const int flat = g * 256 + tid;  // 512 chunks = 64 rows x 8
      const int r = flat >> 3, c = flat & 7;
      const float4 f0 = *(const float4*)(src + r * 64 + c * 8);
      const float4 f1 = *(const float4*)(src + r * 64 + c * 8 + 4);
      const float xs[8] = {f0.x, f0.y, f0.z, f0.w, f1.x, f1.y, f1.z, f1.w};
      bf16x8 hv, lv;
#pragma unroll
      for (int j = 0; j < 8; ++j) {
        const float x = xs[j] * scl;
        const unsigned short h = bf16_rne(x);
        hv[j] = (short)h;
        lv[j] = (short)bf16_rne(x - bf16_to_f(h));
      }
      const int base = (r << 6) + ((c ^ (r & 7)) << 3);
      *(bf16x8*)(dst + base) = hv;
      *(bf16x8*)(dst + 4096 + base) = lv;
      if (!isq) {  // PV/QK-ordered hi copy for Phase C
        const int s_local = ((tl & 1) << 6) + r;
        const int wv = s_local >> 5, mtk = (r >> 4) & 1, kcc = c >> 2, qdd = c & 3;
        *(bf16x8*)(kcd + (wv * 4 + mtk * 2 + kcc) * 512 + qdd * 128 + ((r & 15) << 3)) = hv;
      }
    }
  } else if (jb < 2560) {  // V fragment images (PV consumption order)
    const int jv = jb - 2048;
    const int bh = jv >> 4, tl = jv & 15;
    const float* src = vin + ((size_t)bh * 2048 + tl * 128) * 64;
#pragma unroll
    for (int g = 0; g < 8; ++g) {
      const int f = g * 256 + tid;
      const int r = f >> 4, c4 = f & 15;
      const float4 x = *(const float4*)(src + r * 64 + c4 * 4);
      vld[r][c4 * 4 + 0] = x.x;
      vld[r][c4 * 4 + 1] = x.y;
      vld[r][c4 * 4 + 2] = x.z;
      vld[r][c4 * 4 + 3] = x.w;
    }
    __syncthreads();
    unsigned short* dst = vt_g + (size_t)(bh * 16 + tl) * 8192;
#pragma unroll
    for (int g = 0; g < 4; ++g) {
      const int oc = g * 256 + tid;  // 1024 fragments of 8 bf16
      const int w4 = oc >> 8, dt = (oc >> 6) & 3, qd = (oc >> 4) & 3, l = oc & 15;
      bf16x8 hv;
#pragma unroll
      for (int j = 0; j < 8; ++j)
        hv[j] = (short)bf16_rne(vld[w4 * 32 + qd * 8 + j][dt * 16 + l]);
      *(bf16x8*)(dst + oc * 8) = hv;
    }
  } else {  // zero d_out: 512 blocks x 2048 float4
    float4* o4 = (float4*)out;
    const size_t b = (size_t)(jb - 2560);
#pragma unroll
    for (int g = 0; g < 8; ++g)
      o4[b * 2048 + g * 256 + tid] = make_float4(0.f, 0.f, 0.f, 0.f);
  }
}

// ====== Phase A: partial (Z,W) per (t-row, s-half), bf16x3 MFMA, BK=64 dbuf ======
// grid 1024: bh = b&31 (XCD-local), ttile = (b>>5)&15, shalf = b>>9.
// ROUND-6 LESSON: co-resident same-bh blocks MUST walk the same K stream in
// lockstep (shalf 2-way only). K stays LDS-staged here: all 4 waves read the
// SAME K tile (4-way reuse) — unlike Phase C.
__global__ __launch_bounds__(256, 2) void kl_score_mfma(
    const unsigned short* __restrict__ qimg, const unsigned short* __restrict__ kimg,
    float2* __restrict__ zw) {
  __shared__ __align__(16) unsigned short lbuf[2][8192];  // 2 x 16 KB
  const int b = blockIdx.x;
  const int bh = b & 31;
  const int tt = (b >> 5) & 15;
  const int shalf = b >> 9;
  const int tid = threadIdx.x;
  const int lane = tid & 63, w = tid >> 6, quad = lane >> 4, l15 = lane & 15;
  const unsigned short* qb = qimg + (size_t)(bh * 32 + tt * 2) * 8192;
  const unsigned short* kb = kimg + (size_t)bh * (32 * 8192);
  const int tg0 = shalf * 16;

  // stage the 2 q tiles (rows 0-63 -> lbuf[0], rows 64-127 -> lbuf[1])
  stage_img16(qb, &lbuf[0][0], lane, w);
  stage_img16(qb + 8192, &lbuf[1][0], lane, w);
  __syncthreads();

  bf16x8 ah[2][2], al[2][2];  // persistent q A-fragments (wave w: t-rows w*32..w*32+31)
#pragma unroll
  for (int rt = 0; rt < 2; ++rt) {
    const int row = w * 32 + rt * 16 + l15;
    const unsigned short* lb = &lbuf[row >> 6][0];  // [hi 4096 | lo 4096] per tile
    const int r64 = row & 63;
#pragma unroll
    for (int kc = 0; kc < 2; ++kc) {
      const int off = (r64 << 6) + (((kc * 4 + quad) ^ (r64 & 7)) << 3);
      ah[rt][kc] = *(const bf16x8*)(lb + off);
      al[rt][kc] = *(const bf16x8*)(lb + 4096 + off);
    }
  }
  __syncthreads();  // all q frags in registers; lbuf free

  stage_img16(kb + (size_t)tg0 * 8192, &lbuf[0][0], lane, w);
  __syncthreads();  // drain tile 0

  float Zf[8], Wf[8];
#pragma unroll
  for (int i = 0; i < 8; ++i) { Zf[i] = 0.f; Wf[i] = 0.f; }

  for (int t = 0; t < 16; ++t) {
    if (t < 15)
      stage_img16(kb + (size_t)(tg0 + t + 1) * 8192, &lbuf[(t + 1) & 1][0], lane, w);
    const unsigned short* cb = &lbuf[t & 1][0];  // [hi 4096 | lo 4096] elems, 64 rows

    f32x4 acc[2][4];
#pragma unroll
    for (int rt = 0; rt < 2; ++rt)
#pragma unroll
      for (int ct = 0; ct < 4; ++ct) acc[rt][ct] = (f32x4){0.f, 0.f, 0.f, 0.f};

#pragma unroll
    for (int ct = 0; ct < 4; ++ct) {
      const int srow = ct * 16 + l15;
      const bf16x8 bh0 = ldfrag_sw(cb, srow, quad);
      const bf16x8 bl0 = ldfrag_sw(cb + 4096, srow, quad);
      const bf16x8 bh1 = ldfrag_sw(cb, srow, 4 + quad);
      const bf16x8 bl1 = ldfrag_sw(cb + 4096, srow, 4 + quad);
#pragma unroll
      for (int rt = 0; rt < 2; ++rt) {
        f32x4 c = acc[rt][ct];
        c = __builtin_amdgcn_mfma_f32_16x16x32_bf16(ah[rt][0], bh0, c, 0, 0, 0);
        c = __builtin_amdgcn_mfma_f32_16x16x32_bf16(al[rt][0], bh0, c, 0, 0, 0);
        c = __builtin_amdgcn_mfma_f32_16x16x32_bf16(ah[rt][0], bl0, c, 0, 0, 0);
        c = __builtin_amdgcn_mfma_f32_16x16x32_bf16(ah[rt][1], bh1, c, 0, 0, 0);
        c = __builtin_amdgcn_mfma_f32_16x16x32_bf16(al[rt][1], bh1, c, 0, 0, 0);
        c = __builtin_amdgcn_mfma_f32_16x16x32_bf16(ah[rt][1], bl1, c, 0, 0, 0);
        acc[rt][ct] = c;
      }
    }

    // no-max epilogue (log2 domain): e = 2^t, W += e*t  (fp32 accumulators)
#pragma unroll
    for (int rt = 0; rt < 2; ++rt)
#pragma unroll
      for (int r = 0; r < 4; ++r) {
        float zp = 0.f, wp = 0.f;
#pragma unroll
        for (int ct = 0; ct < 4; ++ct) {
          const float tv = acc[rt][ct][r];
          const float e = EXP2_HW(tv);
          zp += e;
          wp = fmaf(e, tv, wp);
        }
        Zf[rt * 4 + r] += zp;
        Wf[rt * 4 + r] += wp;
      }
    __syncthreads();  // readers done; drains prefetch of t+1
  }

#pragma unroll
  for (int i = 0; i < 8; ++i) {
    float Zt = Zf[i], Wt = Wf[i];
#pragma unroll
    for (int mask = 1; mask <= 8; mask <<= 1) {
      Zt += __shfl_xor(Zt, mask);
      Wt += __shfl_xor(Wt, mask);
    }
    if (l15 == 0) {
      const int row = tt * 128 + w * 32 + (i >> 2) * 16 + quad * 4 + (i & 3);
      zw[((size_t)shalf * 32 + bh) * 2048 + row] = make_float2(Zt, Wt);
    }
  }
}

// ====== Phase B: kl from (Z,W) halves + exact top-614, bitonic, 1024 threads ======
__global__ __launch_bounds__(1024) void topk_kernel(const float2* __restrict__ zw,
                                                    int* __restrict__ topk) {
  __shared__ float sv[2048];
  __shared__ int si[2048];
  const int bh = blockIdx.x;
  const int tid = threadIdx.x;
  for (int i = tid; i < 2048; i += 1024) {
    const float2 a = zw[(size_t)bh * 2048 + i];
    const float2 c = zw[(size_t)(32 + bh) * 2048 + i];
    const double Z = (double)a.x + (double)c.x;
    const double W = (double)a.y + (double)c.y;
    sv[i] = (float)(LN2_D * (W / Z) - log(Z) + LOG_S_D);
    si[i] = i;
  }
  __syncthreads();
  for (int kk = 2; kk <= 2048; kk <<= 1) {
    for (int j = kk >> 1; j > 0; j >>= 1) {
      const int p = tid;
      const int i = ((p & ~(j - 1)) << 1) | (p & (j - 1));
      const int pr = i | j;
      const float v1 = sv[i], v2 = sv[pr];
      const int i1 = si[i], i2 = si[pr];
      const bool beforePI = (v2 > v1) || (v2 == v1 && i2 < i1);
      const bool dirDesc = ((i & kk) == 0);
      const bool doSwap = dirDesc ? beforePI : !beforePI;
      if (doSwap) { sv[i] = v2; sv[pr] = v1; si[i] = i2; si[pr] = i1; }
      __syncthreads();
    }
  }
  for (int i = tid; i < U_SEL; i += 1024) topk[bh * U_SEL + i] = si[i];
}

// ====== Phase C: bf16 MFMA attention, barrier-free + REGISTER DOUBLE-BUFFER ======
// ROUND-13 LESSON: barrier-free alone left the contended-L2 latency (~8k cyc/iter)
// exposed — loads were issued in the same iteration that consumes them. Fix (T14):
// two NAMED K/V register buffer sets (rule #20: never runtime-indexed), loop
// unrolled x2 so LOAD(next) issues before COMPUTE(cur) — vmcnt wait lands after
// a full compute phase. +32 VGPR; LDS ~19 KB; grid 768 = 3 balanced blocks/CU.
struct __align__(16) SmC {
  union { unsigned short qs[QROWS * 64]; unsigned short ps[4][QROWS * 40]; } c;  // 10 KB
  float obuf[QROWS * 64];  // 8 KB
  float zred[4][QROWS];    // 0.5 KB
};

// grid 768: bh = b&31 (XCD-affine), lt = b>>5 in [0,24)
__global__ __launch_bounds__(256, 3) void sparse_attn_mfma(
    const float* __restrict__ q, const unsigned short* __restrict__ kcimg,
    const unsigned short* __restrict__ vt_g, const int* __restrict__ topk,
    float* __restrict__ out) {
  __shared__ SmC sm;
  const int b = blockIdx.x;
  const int bh = b & 31;
  const int l0 = (b >> 5) * QROWS;
  const int tid = threadIdx.x;
  const int lane = tid & 63, w = tid >> 6, quad = lane >> 4, l15 = lane & 15;
  const float* qb = q + (size_t)bh * (2048 * 64);
  const char* kcb = (const char*)(kcimg + (size_t)bh * (16 * 8192));
  const char* vtb = (const char*)(vt_g + (size_t)bh * (16 * 8192));
  const int* tkb = topk + bh * U_SEL;

  {  // gather 32 selected q rows -> bf16 * (0.125*log2e), swizzled image in LDS
    const int r = tid >> 3, c = tid & 7;  // 256 chunks = 32 rows x 8
    const int l = l0 + r;
    const int row = (l < U_SEL) ? tkb[l] : tkb[0];
    const float4 f0 = *(const float4*)(qb + (size_t)row * 64 + c * 8);
    const float4 f1 = *(const float4*)(qb + (size_t)row * 64 + c * 8 + 4);
    const float xs[8] = {f0.x, f0.y, f0.z, f0.w, f1.x, f1.y, f1.z, f1.w};
    bf16x8 hv;
#pragma unroll
    for (int j = 0; j < 8; ++j) hv[j] = (short)bf16_rne(xs[j] * SCL_Q);
    *(bf16x8*)&sm.c.qs[(r << 6) + ((c ^ (r & 7)) << 3)] = hv;
  }
  __syncthreads();  // qs ready

  bf16x8 qf[2][2];  // persistent q B-fragments (32 rows -> 2 nt tiles)
#pragma unroll
  for (int nt = 0; nt < 2; ++nt)
#pragma unroll
    for (int kc = 0; kc < 2; ++kc)
      qf[nt][kc] = ldfrag_sw(sm.c.qs, nt * 16 + l15, kc * 4 + quad);
  __syncthreads();  // all waves done reading qs; ps (same bytes) may be written

  float zrun[2] = {0.f, 0.f};
  f32x4 oacc[2][4];
#pragma unroll
  for (int a = 0; a < 2; ++a)
#pragma unroll
    for (int b2 = 0; b2 < 4; ++b2) oacc[a][b2] = (f32x4){0.f, 0.f, 0.f, 0.f};

  const int kvbase = (w * 4) << 10;  // wave's 4 KB block within each 16 KB tile

#define LOADKV(AF, VB, ST)                                                     \
  do {                                                                         \
    const char* kp_ = kcb + (size_t)(ST) * 16384 + kvbase + lane * 16;         \
    const char* vp_ = vtb + (size_t)(ST) * 16384 + kvbase + lane * 16;         \
    (AF)[0][0] = *(const bf16x8*)(kp_);                                        \
    (AF)[0][1] = *(const bf16x8*)(kp_ + 1024);                                 \
    (AF)[1][0] = *(const bf16x8*)(kp_ + 2048);                                 \
    (AF)[1][1] = *(const bf16x8*)(kp_ + 3072);                                 \
    (VB)[0] = *(const bf16x8*)(vp_);                                           \
    (VB)[1] = *(const bf16x8*)(vp_ + 1024);                                    \
    (VB)[2] = *(const bf16x8*)(vp_ + 2048);                                    \
    (VB)[3] = *(const bf16x8*)(vp_ + 3072);                                    \
  } while (0)

#define COMPUTE(AF, VB)                                                        \
  do {                                                                         \
    f32x4 sacc[2][2];                                                          \
    __builtin_amdgcn_s_setprio(1);                                             \
    _Pragma("unroll") for (int mt = 0; mt < 2; ++mt)                           \
        _Pragma("unroll") for (int nt = 0; nt < 2; ++nt) {                     \
      f32x4 c = (f32x4){0.f, 0.f, 0.f, 0.f};                                   \
      c = __builtin_amdgcn_mfma_f32_16x16x32_bf16((AF)[mt][0], qf[nt][0], c, 0, 0, 0); \
      c = __builtin_amdgcn_mfma_f32_16x16x32_bf16((AF)[mt][1], qf[nt][1], c, 0, 0, 0); \
      sacc[mt][nt] = c;                                                        \
    }                                                                          \
    __builtin_amdgcn_s_setprio(0);                                             \
    _Pragma("unroll") for (int nt = 0; nt < 2; ++nt) {                         \
      float zl = 0.f;                                                          \
      _Pragma("unroll") for (int mt = 0; mt < 2; ++mt) {                       \
        bf16x4 pw;                                                             \
        _Pragma("unroll") for (int r = 0; r < 4; ++r) {                        \
          const float p = EXP2_HW(sacc[mt][nt][r]);                            \
          zl += p;                                                             \
          pw[r] = (short)bf16_rne(p);                                          \
        }                                                                      \
        *(bf16x4*)&sm.c.ps[w][(nt * 16 + l15) * 40 + mt * 16 + quad * 4] = pw; \
      }                                                                        \
      zrun[nt] += zl;                                                          \
    }                                                                          \
    __builtin_amdgcn_s_setprio(1);                                             \
    _Pragma("unroll") for (int mtq = 0; mtq < 2; ++mtq) {                      \
      const bf16x8 pa = *(const bf16x8*)&sm.c.ps[w][(mtq * 16 + l15) * 40 + quad * 8]; \
      _Pragma("unroll") for (int dt = 0; dt < 4; ++dt)                         \
        oacc[mtq][dt] = __builtin_amdgcn_mfma_f32_16x16x32_bf16(pa, (VB)[dt], oacc[mtq][dt], 0, 0, 0); \
    }                                                                          \
    __builtin_amdgcn_s_setprio(0);                                             \
  } while (0)

  bf16x8 afA[2][2], vbfA[4], afB[2][2], vbfB[4];
  LOADKV(afA, vbfA, 0);
  for (int st = 0; st < 16; st += 2) {
    LOADKV(afB, vbfB, st + 1);  // issue next tile's loads BEFORE computing cur
    COMPUTE(afA, vbfA);
    if (st + 2 < 16) LOADKV(afA, vbfA, st + 2);
    COMPUTE(afB, vbfB);
  }
#undef LOADKV
#undef COMPUTE

  // Z: reduce over quads in-wave, stash per-wave rows
#pragma unroll
  for (int nt = 0; nt < 2; ++nt) {
    float z = zrun[nt];
    z += __shfl_xor(z, 16);
    z += __shfl_xor(z, 32);
    if (quad == 0) sm.zred[w][nt * 16 + l15] = z;
  }
  for (int i = tid; i < QROWS * 64; i += 256) sm.obuf[i] = 0.f;
  __syncthreads();
#pragma unroll
  for (int mtq = 0; mtq < 2; ++mtq)
#pragma unroll
    for (int r = 0; r < 4; ++r) {
      const int qr = mtq * 16 + quad * 4 + r;
#pragma unroll
      for (int dt = 0; dt < 4; ++dt)
        atomicAdd(&sm.obuf[qr * 64 + dt * 16 + l15], oacc[mtq][dt][r]);
    }
  __syncthreads();
  {  // normalized direct store: 32 rows x 4 segs = 128 work items
    if (tid < QROWS * 4) {
      const int qr = tid >> 2, seg = tid & 3;
      const int l = l0 + qr;
      if (l < U_SEL) {
        const float Zt = sm.zred[0][qr] + sm.zred[1][qr] +
                         sm.zred[2][qr] + sm.zred[3][qr];
        const float inv = 1.0f / Zt;
        const int row = tkb[l];
        float* op = &out[((size_t)bh * T_DIM + row) * 64 + seg * 16];
        const float* ob = &sm.obuf[qr * 64 + seg * 16];
#pragma unroll
        for (int j = 0; j < 4; ++j) {
          float4 o;
          o.x = ob[j * 4 + 0] * inv;
          o.y = ob[j * 4 + 1] * inv;
          o.z = ob[j * 4 + 2] * inv;
          o.w = ob[j * 4 + 3] * inv;
          *(float4*)&op[j * 4] = o;
        }
      }
    }
  }
}

extern "C" void kernel_launch(void* const* d_in, const int* in_sizes, int n_in,
                              void* d_out, int out_size, void* d_ws, size_t ws_size,
                              hipStream_t stream) {
  const float* q = (const float*)d_in[0];
  const float* k = (const float*)d_in[1];
  const float* v = (const float*)d_in[2];
  float* out = (float*)d_out;
  // workspace: zw 1MB | topk 80KB | kimg 16MB | vt 8MB | qimg 16MB | kcimg 8MB (~49.3MB)
  char* ws = (char*)d_ws;
  float2* zw = (float2*)ws;                                  // [2][32][2048] float2
  int* topk = (int*)(ws + 1048576);
  unsigned short* kimg = (unsigned short*)(ws + 1310720);    // 32 bh x 32 tiles x 16 KB
  unsigned short* vt_g = (unsigned short*)(ws + 18087936);   // 32 bh x 16 tiles x 16 KB
  unsigned short* qimg = (unsigned short*)(ws + 26476544);   // 32 bh x 32 tiles x 16 KB
  unsigned short* kcimg = (unsigned short*)(ws + 43253760);  // 32 bh x 16 tiles x 16 KB

  convert_kernel<<<dim3(3072), dim3(256), 0, stream>>>(k, v, q, kimg, vt_g, qimg, kcimg, out);
  kl_score_mfma<<<dim3(1024), dim3(256), 0, stream>>>(qimg, kimg, zw);
  topk_kernel<<<dim3(BH_DIM), dim3(1024), 0, stream>>>(zw, topk);
  sparse_attn_mfma<<<dim3(768), dim3(256), 0, stream>>>(q, kcimg, vt_g, topk, out);
}